// Round 1
// baseline (185.083 us; speedup 1.0000x reference)
//
#include <hip/hip_runtime.h>
#include <math.h>

#define BATCH 8
#define SEQ   4096
#define DM    128   // D_MODEL
#define DS    128   // D_STATE
#define NFFT  8192
#define NT    256

__device__ __forceinline__ float2 cmulf(float2 a, float2 b) {
    return make_float2(a.x * b.x - a.y * b.y, a.x * b.y + a.y * b.x);
}

// G = C @ B  (both 128x128 row-major)
__global__ void prep_G(const float* __restrict__ Cm, const float* __restrict__ Bm,
                       float* __restrict__ G) {
    int gid = blockIdx.x * blockDim.x + threadIdx.x;   // 0..16383
    int m = gid >> 7, j = gid & 127;
    float acc = 0.f;
    for (int i = 0; i < DS; ++i) acc += Cm[m * DS + i] * Bm[i * DM + j];
    G[gid] = acc;
}

// Psum[s,l] = sum_m exp(dt[m] * Lam[s] * l)
__global__ void prep_psum(const float* __restrict__ Lam, const float* __restrict__ logdt,
                          float* __restrict__ Psum) {
    __shared__ float sdt[DM];
    int tid = threadIdx.x;
    if (tid < DM) sdt[tid] = __expf(logdt[tid]);
    __syncthreads();
    int s = blockIdx.x;
    int l = blockIdx.y * NT + tid;
    float t = Lam[s] * (float)l;
    float acc = 0.f;
    for (int m = 0; m < DM; ++m) acc += __expf(sdt[m] * t);
    Psum[s * SEQ + l] = acc;
}

// K[m,l] = sum_s G[m,s] * Psum[s,l]
__global__ void prep_K(const float* __restrict__ G, const float* __restrict__ Psum,
                       float* __restrict__ K) {
    int m = blockIdx.y;
    int l = blockIdx.x * NT + threadIdx.x;
    float acc = 0.f;
    for (int s = 0; s < DS; ++s) acc += G[m * DS + s] * Psum[s * SEQ + l];
    K[m * SEQ + l] = acc;
}

// Kf[m] = DIF-FFT(zero-padded K[m]), left in bit-reversed order.
__global__ void __launch_bounds__(NT) fft_K(const float* __restrict__ K,
                                            float2* __restrict__ Kf) {
    __shared__ float2 z[NFFT];
    int tid = threadIdx.x, m = blockIdx.x;
    for (int k = 0; k < 16; ++k) {
        int l = tid + (k << 8);
        z[l]       = make_float2(K[m * SEQ + l], 0.f);
        z[l + SEQ] = make_float2(0.f, 0.f);
    }
    __syncthreads();
    for (int mh = NFFT / 2; mh >= 1; mh >>= 1) {
        float astep = -(float)M_PI / (float)mh;
        for (int k = 0; k < 16; ++k) {
            int idx = tid + (k << 8);
            int j  = idx & (mh - 1);
            int i0 = ((idx & ~(mh - 1)) << 1) | j;
            int i1 = i0 + mh;
            float2 a = z[i0], b = z[i1];
            float sn, cs;
            __sincosf(astep * (float)j, &sn, &cs);
            z[i0] = make_float2(a.x + b.x, a.y + b.y);
            float2 d = make_float2(a.x - b.x, a.y - b.y);
            z[i1] = make_float2(d.x * cs - d.y * sn, d.x * sn + d.y * cs);
        }
        __syncthreads();
    }
    for (int k = 0; k < 32; ++k) {
        int i = tid + (k << 8);
        Kf[(size_t)m * NFFT + i] = z[i];
    }
}

// x (B,L,M) -> xt (B,M,L)
__global__ void transpose_xin(const float* __restrict__ x, float* __restrict__ xt) {
    __shared__ float tile[32][33];
    int b = blockIdx.z;
    int l0 = blockIdx.x * 32, m0 = blockIdx.y * 32;
    int tx = threadIdx.x, ty = threadIdx.y;
    for (int r = 0; r < 4; ++r) {
        int l = l0 + ty + r * 8;
        tile[ty + r * 8][tx] = x[(size_t)b * SEQ * DM + (size_t)l * DM + m0 + tx];
    }
    __syncthreads();
    for (int r = 0; r < 4; ++r) {
        int m = m0 + ty + r * 8;
        xt[(size_t)b * DM * SEQ + (size_t)m * SEQ + l0 + tx] = tile[tx][ty + r * 8];
    }
}

// yt (B,M,L) -> out (B,L,M)
__global__ void transpose_yout(const float* __restrict__ yt, float* __restrict__ out) {
    __shared__ float tile[32][33];
    int b = blockIdx.z;
    int l0 = blockIdx.x * 32, m0 = blockIdx.y * 32;
    int tx = threadIdx.x, ty = threadIdx.y;
    for (int r = 0; r < 4; ++r) {
        int m = m0 + ty + r * 8;
        tile[ty + r * 8][tx] = yt[(size_t)b * DM * SEQ + (size_t)m * SEQ + l0 + tx];
    }
    __syncthreads();
    for (int r = 0; r < 4; ++r) {
        int l = l0 + ty + r * 8;
        out[(size_t)b * SEQ * DM + (size_t)l * DM + m0 + tx] = tile[tx][ty + r * 8];
    }
}

// Two-for-one FFT convolution: z = x[b0,m] + i*x[b1,m]; y = IFFT(FFT(z)*Kf).
// Writes results in-place over xt rows (each WG owns its two rows).
__global__ void __launch_bounds__(NT) conv_fft(float* __restrict__ xt,
                                               const float2* __restrict__ Kf,
                                               const float* __restrict__ Dv) {
    __shared__ float2 z[NFFT];
    int tid = threadIdx.x;
    int m  = blockIdx.x & (DM - 1);
    int bp = blockIdx.x >> 7;            // 0..3
    size_t base0 = ((size_t)(2 * bp) * DM + m) * SEQ;
    size_t base1 = ((size_t)(2 * bp + 1) * DM + m) * SEQ;

    for (int k = 0; k < 16; ++k) {
        int l = tid + (k << 8);
        z[l]       = make_float2(xt[base0 + l], xt[base1 + l]);
        z[l + SEQ] = make_float2(0.f, 0.f);
    }
    __syncthreads();

    // Forward DIF: natural -> bit-reversed
    for (int mh = NFFT / 2; mh >= 1; mh >>= 1) {
        float astep = -(float)M_PI / (float)mh;
        for (int k = 0; k < 16; ++k) {
            int idx = tid + (k << 8);
            int j  = idx & (mh - 1);
            int i0 = ((idx & ~(mh - 1)) << 1) | j;
            int i1 = i0 + mh;
            float2 a = z[i0], b = z[i1];
            float sn, cs;
            __sincosf(astep * (float)j, &sn, &cs);
            z[i0] = make_float2(a.x + b.x, a.y + b.y);
            float2 d = make_float2(a.x - b.x, a.y - b.y);
            z[i1] = make_float2(d.x * cs - d.y * sn, d.x * sn + d.y * cs);
        }
        __syncthreads();
    }

    // Pointwise multiply in bit-reversed domain (elementwise -> no sync needed inside)
    for (int k = 0; k < 32; ++k) {
        int i = tid + (k << 8);
        z[i] = cmulf(z[i], Kf[(size_t)m * NFFT + i]);
    }
    __syncthreads();

    // Inverse DIT: bit-reversed -> natural (conjugated twiddles)
    for (int mh = 1; mh <= NFFT / 2; mh <<= 1) {
        float astep = (float)M_PI / (float)mh;
        for (int k = 0; k < 16; ++k) {
            int idx = tid + (k << 8);
            int j  = idx & (mh - 1);
            int i0 = ((idx & ~(mh - 1)) << 1) | j;
            int i1 = i0 + mh;
            float2 a = z[i0], b = z[i1];
            float sn, cs;
            __sincosf(astep * (float)j, &sn, &cs);
            float2 t = make_float2(b.x * cs - b.y * sn, b.x * sn + b.y * cs);
            z[i0] = make_float2(a.x + t.x, a.y + t.y);
            z[i1] = make_float2(a.x - t.x, a.y - t.y);
        }
        __syncthreads();
    }

    const float invN = 1.0f / (float)NFFT;
    float dv = Dv[m];
    for (int k = 0; k < 16; ++k) {
        int l = tid + (k << 8);
        float xv0 = xt[base0 + l];
        float xv1 = xt[base1 + l];
        xt[base0 + l] = z[l].x * invN + dv * xv0;
        xt[base1 + l] = z[l].y * invN + dv * xv1;
    }
}

extern "C" void kernel_launch(void* const* d_in, const int* in_sizes, int n_in,
                              void* d_out, int out_size, void* d_ws, size_t ws_size,
                              hipStream_t stream) {
    const float* x     = (const float*)d_in[0];
    const float* Lam   = (const float*)d_in[1];
    const float* Bm    = (const float*)d_in[2];
    const float* Cm    = (const float*)d_in[3];
    const float* Dv    = (const float*)d_in[4];
    const float* logdt = (const float*)d_in[5];
    float* out = (float*)d_out;

    float*  ws   = (float*)d_ws;
    float*  xt   = ws;                               // 4,194,304 floats (16 MB)
    float2* Kf   = (float2*)(ws + 4194304);          // 2,097,152 floats (8 MB)
    float*  K    = ws + 4194304 + 2097152;           // 524,288 floats (2 MB)
    float*  Psum = K + 524288;                       // 524,288 floats (2 MB)
    float*  G    = Psum + 524288;                    // 16,384 floats
    // total ws use: 7,356,416 floats = ~28.1 MB

    hipLaunchKernelGGL(prep_G,       dim3(64),          dim3(NT),     0, stream, Cm, Bm, G);
    hipLaunchKernelGGL(prep_psum,    dim3(128, 16),     dim3(NT),     0, stream, Lam, logdt, Psum);
    hipLaunchKernelGGL(prep_K,       dim3(16, 128),     dim3(NT),     0, stream, G, Psum, K);
    hipLaunchKernelGGL(fft_K,        dim3(128),         dim3(NT),     0, stream, K, Kf);
    hipLaunchKernelGGL(transpose_xin, dim3(128, 4, 8),  dim3(32, 8),  0, stream, x, xt);
    hipLaunchKernelGGL(conv_fft,     dim3(512),         dim3(NT),     0, stream, xt, Kf, Dv);
    hipLaunchKernelGGL(transpose_yout, dim3(128, 4, 8), dim3(32, 8),  0, stream, xt, out);
}

// Round 2
// 147.699 us; speedup vs baseline: 1.2531x; 1.2531x over previous
//
#include <hip/hip_runtime.h>
#include <math.h>

#define BATCH 8
#define SEQ   4096
#define DM    128   // D_MODEL
#define DS    128   // D_STATE
#define NFFT  8192
#define NT    512   // threads for FFT kernels
#define NTP   256   // threads for prep kernels
#define NBUT  (NFFT / 4)    // 2048 radix-4 butterflies per stage
#define PERT  (NBUT / NT)   // 4 butterflies per thread

__device__ __forceinline__ float2 cmulf(float2 a, float2 b) {
    return make_float2(a.x * b.x - a.y * b.y, a.x * b.y + a.y * b.x);
}
__device__ __forceinline__ float2 caddf(float2 a, float2 b) { return make_float2(a.x + b.x, a.y + b.y); }
__device__ __forceinline__ float2 csubf(float2 a, float2 b) { return make_float2(a.x - b.x, a.y - b.y); }

// ---------------- prep kernels ----------------

// G = C @ B  (both 128x128 row-major)
__global__ void prep_G(const float* __restrict__ Cm, const float* __restrict__ Bm,
                       float* __restrict__ G) {
    int gid = blockIdx.x * blockDim.x + threadIdx.x;   // 0..16383
    int m = gid >> 7, j = gid & 127;
    float acc = 0.f;
    for (int i = 0; i < DS; ++i) acc += Cm[m * DS + i] * Bm[i * DM + j];
    G[gid] = acc;
}

// Psum[s,l] = sum_m exp(dt[m] * Lam[s] * l)
__global__ void prep_psum(const float* __restrict__ Lam, const float* __restrict__ logdt,
                          float* __restrict__ Psum) {
    __shared__ float sdt[DM];
    int tid = threadIdx.x;
    if (tid < DM) sdt[tid] = __expf(logdt[tid]);
    __syncthreads();
    int s = blockIdx.x;
    int l = blockIdx.y * NTP + tid;
    float t = Lam[s] * (float)l;
    float acc = 0.f;
    for (int m = 0; m < DM; ++m) acc += __expf(sdt[m] * t);
    Psum[s * SEQ + l] = acc;
}

// K[m,l] = sum_s G[m,s] * Psum[s,l]
__global__ void prep_K(const float* __restrict__ G, const float* __restrict__ Psum,
                       float* __restrict__ K) {
    int m = blockIdx.y;
    int l = blockIdx.x * NTP + threadIdx.x;
    float acc = 0.f;
    for (int s = 0; s < DS; ++s) acc += G[m * DS + s] * Psum[s * SEQ + l];
    K[m * SEQ + l] = acc;
}

// ---------------- radix-4 stages (in-place DIF, LDS-resident) ----------------

// forward radix-4 DIF stage, quarter q (span 4q)
__device__ __forceinline__ void r4_fwd(float2* z, int tid, int q) {
    const float astep = -(float)M_PI / (2.0f * (float)q);   // -2*pi/(4q)
#pragma unroll
    for (int k = 0; k < PERT; ++k) {
        int idx = tid + k * NT;
        int j = idx & (q - 1);
        int base = ((idx & ~(q - 1)) << 2) | j;
        float2 a0 = z[base], a1 = z[base + q], a2 = z[base + 2 * q], a3 = z[base + 3 * q];
        float sn, cs; __sincosf(astep * (float)j, &sn, &cs);
        float2 w1 = make_float2(cs, sn);
        float2 w2 = cmulf(w1, w1);
        float2 w3 = cmulf(w1, w2);
        float2 t0 = caddf(a0, a2), t1 = csubf(a0, a2);
        float2 t2 = caddf(a1, a3), t3 = csubf(a1, a3);
        z[base]         = caddf(t0, t2);
        z[base + q]     = cmulf(make_float2(t1.x + t3.y, t1.y - t3.x), w1); // (t1 - i t3) w1
        z[base + 2 * q] = cmulf(csubf(t0, t2), w2);
        z[base + 3 * q] = cmulf(make_float2(t1.x - t3.y, t1.y + t3.x), w3); // (t1 + i t3) w3
    }
}

// inverse radix-4 stage: exact inverse of r4_fwd times 4 (scaling absorbed in invN)
__device__ __forceinline__ void r4_inv(float2* z, int tid, int q) {
    const float astep = (float)M_PI / (2.0f * (float)q);    // +2*pi/(4q) (conjugate twiddles)
#pragma unroll
    for (int k = 0; k < PERT; ++k) {
        int idx = tid + k * NT;
        int j = idx & (q - 1);
        int base = ((idx & ~(q - 1)) << 2) | j;
        float2 y0 = z[base], y1 = z[base + q], y2 = z[base + 2 * q], y3 = z[base + 3 * q];
        float sn, cs; __sincosf(astep * (float)j, &sn, &cs);
        float2 w1 = make_float2(cs, sn);
        float2 w2 = cmulf(w1, w1);
        float2 w3 = cmulf(w1, w2);
        float2 b1 = cmulf(y1, w1), b2 = cmulf(y2, w2), b3 = cmulf(y3, w3);
        float2 t0 = caddf(y0, b2), t2 = csubf(y0, b2);
        float2 t1 = caddf(b1, b3);
        float2 t3 = make_float2(-(b1.y - b3.y), b1.x - b3.x);  // i*(b1-b3)
        z[base]         = caddf(t0, t1);
        z[base + 2 * q] = csubf(t0, t1);
        z[base + q]     = caddf(t2, t3);
        z[base + 3 * q] = csubf(t2, t3);
    }
}

// ---------------- Kf = forward FFT of zero-padded K (scrambled radix-4 order) ----------------

__global__ void __launch_bounds__(NT, 4) fft_K(const float* __restrict__ K,
                                               float2* __restrict__ Kf) {
    __shared__ __align__(16) float2 z[NFFT];
    int tid = threadIdx.x, m = blockIdx.x;

    // fused load + first fwd stage (q=2048); inputs real, upper half zero
    {
        const float astep = -(float)M_PI / 4096.0f;   // -2*pi/8192
#pragma unroll
        for (int k = 0; k < PERT; ++k) {
            int j = tid + k * NT;                     // 0..2047
            float a0 = K[m * SEQ + j];
            float a1 = K[m * SEQ + j + 2048];
            float sn, cs; __sincosf(astep * (float)j, &sn, &cs);
            float2 w1 = make_float2(cs, sn);
            float2 w2 = cmulf(w1, w1);
            float2 w3 = cmulf(w1, w2);
            z[j]        = make_float2(a0 + a1, 0.f);
            z[j + 2048] = cmulf(make_float2(a0, -a1), w1);       // (a0 - i a1) w1
            z[j + 4096] = cmulf(make_float2(a0 - a1, 0.f), w2);
            z[j + 6144] = cmulf(make_float2(a0,  a1), w3);       // (a0 + i a1) w3
        }
    }
    __syncthreads();
    r4_fwd(z, tid, 512); __syncthreads();
    r4_fwd(z, tid, 128); __syncthreads();
    r4_fwd(z, tid, 32);  __syncthreads();
    r4_fwd(z, tid, 8);   __syncthreads();
    r4_fwd(z, tid, 2);   __syncthreads();
    // final forward radix-2 (twiddle-free) fused with store
    {
        const float4* z4 = (const float4*)z;
        float4* kf4 = (float4*)(Kf + (size_t)m * NFFT);
#pragma unroll
        for (int k = 0; k < NFFT / 2 / NT; ++k) {     // 8 pairs/thread
            int i = tid + k * NT;
            float4 p = z4[i];
            kf4[i] = make_float4(p.x + p.z, p.y + p.w, p.x - p.z, p.y - p.w);
        }
    }
}

// ---------------- transposes ----------------

// x (B,L,M) -> xt (B,M,L)
__global__ void transpose_xin(const float* __restrict__ x, float* __restrict__ xt) {
    __shared__ float tile[32][33];
    int b = blockIdx.z;
    int l0 = blockIdx.x * 32, m0 = blockIdx.y * 32;
    int tx = threadIdx.x, ty = threadIdx.y;
    for (int r = 0; r < 4; ++r) {
        int l = l0 + ty + r * 8;
        tile[ty + r * 8][tx] = x[(size_t)b * SEQ * DM + (size_t)l * DM + m0 + tx];
    }
    __syncthreads();
    for (int r = 0; r < 4; ++r) {
        int m = m0 + ty + r * 8;
        xt[(size_t)b * DM * SEQ + (size_t)m * SEQ + l0 + tx] = tile[tx][ty + r * 8];
    }
}

// yt (B,M,L) -> out (B,L,M)
__global__ void transpose_yout(const float* __restrict__ yt, float* __restrict__ out) {
    __shared__ float tile[32][33];
    int b = blockIdx.z;
    int l0 = blockIdx.x * 32, m0 = blockIdx.y * 32;
    int tx = threadIdx.x, ty = threadIdx.y;
    for (int r = 0; r < 4; ++r) {
        int m = m0 + ty + r * 8;
        tile[ty + r * 8][tx] = yt[(size_t)b * DM * SEQ + (size_t)m * SEQ + l0 + tx];
    }
    __syncthreads();
    for (int r = 0; r < 4; ++r) {
        int l = l0 + ty + r * 8;
        out[(size_t)b * SEQ * DM + (size_t)l * DM + m0 + tx] = tile[tx][ty + r * 8];
    }
}

// ---------------- main convolution: two-for-one complex packing ----------------
// z = x[b0,m] + i*x[b1,m]; y = IFFT(FFT(z) * Kf); real/imag give the two batches.

__global__ void __launch_bounds__(NT, 4) conv_fft(float* __restrict__ xt,
                                                  const float2* __restrict__ Kf,
                                                  const float* __restrict__ Dv) {
    __shared__ __align__(16) float2 z[NFFT];
    int tid = threadIdx.x;
    int m  = blockIdx.x & (DM - 1);
    int bp = blockIdx.x >> 7;            // 0..3
    size_t base0 = ((size_t)(2 * bp) * DM + m) * SEQ;
    size_t base1 = ((size_t)(2 * bp + 1) * DM + m) * SEQ;

    // fused load + first fwd stage (q=2048); upper half of padded input is zero
    {
        const float astep = -(float)M_PI / 4096.0f;
#pragma unroll
        for (int k = 0; k < PERT; ++k) {
            int j = tid + k * NT;        // 0..2047
            float2 a0 = make_float2(xt[base0 + j],        xt[base1 + j]);
            float2 a1 = make_float2(xt[base0 + j + 2048], xt[base1 + j + 2048]);
            float sn, cs; __sincosf(astep * (float)j, &sn, &cs);
            float2 w1 = make_float2(cs, sn);
            float2 w2 = cmulf(w1, w1);
            float2 w3 = cmulf(w1, w2);
            z[j]        = caddf(a0, a1);
            z[j + 2048] = cmulf(make_float2(a0.x + a1.y, a0.y - a1.x), w1); // (a0 - i a1) w1
            z[j + 4096] = cmulf(csubf(a0, a1), w2);
            z[j + 6144] = cmulf(make_float2(a0.x - a1.y, a0.y + a1.x), w3); // (a0 + i a1) w3
        }
    }
    __syncthreads();
    r4_fwd(z, tid, 512); __syncthreads();
    r4_fwd(z, tid, 128); __syncthreads();
    r4_fwd(z, tid, 32);  __syncthreads();
    r4_fwd(z, tid, 8);   __syncthreads();
    r4_fwd(z, tid, 2);   __syncthreads();

    // fused: fwd radix-2 + pointwise *Kf + inv radix-2 — all on the same (2i,2i+1) pair
    {
        float4* z4 = (float4*)z;
        const float4* kf4 = (const float4*)(Kf + (size_t)m * NFFT);
#pragma unroll
        for (int k = 0; k < NFFT / 2 / NT; ++k) {     // 8 pairs/thread
            int i = tid + k * NT;
            float4 p = z4[i];
            float2 u0 = make_float2(p.x + p.z, p.y + p.w);
            float2 u1 = make_float2(p.x - p.z, p.y - p.w);
            float4 kk = kf4[i];
            u0 = cmulf(u0, make_float2(kk.x, kk.y));
            u1 = cmulf(u1, make_float2(kk.z, kk.w));
            z4[i] = make_float4(u0.x + u1.x, u0.y + u1.y, u0.x - u1.x, u0.y - u1.y);
        }
    }
    __syncthreads();
    r4_inv(z, tid, 2);   __syncthreads();
    r4_inv(z, tid, 8);   __syncthreads();
    r4_inv(z, tid, 32);  __syncthreads();
    r4_inv(z, tid, 128); __syncthreads();
    r4_inv(z, tid, 512); __syncthreads();

    // fused final inverse stage (q=2048): only lower 4096 outputs needed
    {
        const float astep = (float)M_PI / 4096.0f;
        const float invN = 1.0f / (float)NFFT;
        float dv = Dv[m];
#pragma unroll
        for (int k = 0; k < PERT; ++k) {
            int j = tid + k * NT;
            float2 y0 = z[j], y1 = z[j + 2048], y2 = z[j + 4096], y3 = z[j + 6144];
            float sn, cs; __sincosf(astep * (float)j, &sn, &cs);
            float2 w1 = make_float2(cs, sn);
            float2 w2 = cmulf(w1, w1);
            float2 w3 = cmulf(w1, w2);
            float2 b1 = cmulf(y1, w1), b2 = cmulf(y2, w2), b3 = cmulf(y3, w3);
            float2 t0 = caddf(y0, b2), t2 = csubf(y0, b2);
            float2 t1 = caddf(b1, b3);
            float2 t3 = make_float2(-(b1.y - b3.y), b1.x - b3.x);
            float2 r0 = caddf(t0, t1);   // natural index j
            float2 r1 = caddf(t2, t3);   // natural index j+2048
            float x00 = xt[base0 + j],        x10 = xt[base1 + j];
            float x01 = xt[base0 + j + 2048], x11 = xt[base1 + j + 2048];
            xt[base0 + j]        = r0.x * invN + dv * x00;
            xt[base1 + j]        = r0.y * invN + dv * x10;
            xt[base0 + j + 2048] = r1.x * invN + dv * x01;
            xt[base1 + j + 2048] = r1.y * invN + dv * x11;
        }
    }
}

extern "C" void kernel_launch(void* const* d_in, const int* in_sizes, int n_in,
                              void* d_out, int out_size, void* d_ws, size_t ws_size,
                              hipStream_t stream) {
    const float* x     = (const float*)d_in[0];
    const float* Lam   = (const float*)d_in[1];
    const float* Bm    = (const float*)d_in[2];
    const float* Cm    = (const float*)d_in[3];
    const float* Dv    = (const float*)d_in[4];
    const float* logdt = (const float*)d_in[5];
    float* out = (float*)d_out;

    float*  ws   = (float*)d_ws;
    float*  xt   = ws;                               // 4,194,304 floats (16 MB)
    float2* Kf   = (float2*)(ws + 4194304);          // 2,097,152 floats (8 MB)
    float*  K    = ws + 4194304 + 2097152;           // 524,288 floats (2 MB)
    float*  Psum = K + 524288;                       // 524,288 floats (2 MB)
    float*  G    = Psum + 524288;                    // 16,384 floats

    hipLaunchKernelGGL(prep_G,         dim3(64),         dim3(NTP),    0, stream, Cm, Bm, G);
    hipLaunchKernelGGL(prep_psum,      dim3(128, 16),    dim3(NTP),    0, stream, Lam, logdt, Psum);
    hipLaunchKernelGGL(prep_K,         dim3(16, 128),    dim3(NTP),    0, stream, G, Psum, K);
    hipLaunchKernelGGL(fft_K,          dim3(128),        dim3(NT),     0, stream, K, Kf);
    hipLaunchKernelGGL(transpose_xin,  dim3(128, 4, 8),  dim3(32, 8),  0, stream, x, xt);
    hipLaunchKernelGGL(conv_fft,       dim3(512),        dim3(NT),     0, stream, xt, Kf, Dv);
    hipLaunchKernelGGL(transpose_yout, dim3(128, 4, 8),  dim3(32, 8),  0, stream, xt, out);
}